// Round 1
// baseline (793.190 us; speedup 1.0000x reference)
//
#include <hip/hip_runtime.h>

#define N_SEQ 512
#define N_RES 384
#define C_M   256
#define C_OUT 32
#define C_Z   128

typedef __bf16 bf16;
typedef __bf16 bf16x4 __attribute__((ext_vector_type(4)));
typedef __bf16 bf16x8 __attribute__((ext_vector_type(8)));
typedef float  f32x4  __attribute__((ext_vector_type(4)));

// Workspace layout (bytes):
//   leftT  [12288][512] bf16 @ 0           (m=b*32+c, k=a)   12,582,912
//   rightT [12288][512] bf16 @ 12,582,912  (n=d*32+e, k=a)   12,582,912
//   WtEp   [128][1024]  bf16 @ 25,165,824  (f, ce)              262,144
//   projWt [64][256]    bf16 @ 25,427,968  (o, m)                32,768
//   recip  [384*384]    f32  @ 25,460,736                       589,824
// total ~26.05 MB

// ---------------- prep: transpose weights to bf16 ----------------
__global__ void prep_kernel(const float* __restrict__ lw, const float* __restrict__ rw,
                            const float* __restrict__ ow,
                            bf16* __restrict__ projWt, bf16* __restrict__ WtEp) {
  int idx = blockIdx.x * 256 + threadIdx.x;
  if (idx < 64 * 256) {
    int o = idx >> 8, m = idx & 255;
    float v = (o < 32) ? lw[m * 32 + o] : rw[m * 32 + (o - 32)];
    projWt[idx] = (bf16)v;               // projWt[o][m]
  } else {
    int i2 = idx - 64 * 256;             // [0, 131072)
    int f = i2 >> 10, k = i2 & 1023;     // k = c*32+e
    WtEp[i2] = (bf16)ow[k * 128 + f];    // WtEp[f][k]
  }
}

// ---------------- norm: recip[b][d] = 1/(eps + sum_a m[a,b] m[a,d]) ----------------
__global__ void norm_kernel(const float* __restrict__ mask, float* __restrict__ recip) {
  int b = blockIdx.x * 16 + threadIdx.x;
  int d = blockIdx.y * 16 + threadIdx.y;
  float s = 0.f;
#pragma unroll 8
  for (int a = 0; a < N_SEQ; ++a)
    s += mask[a * N_RES + b] * mask[a * N_RES + d];
  recip[b * N_RES + d] = 1.0f / (1e-3f + s);
}

// ---------------- LN + projection (MFMA), writes leftT/rightT ----------------
// block: 128 a-rows, fixed b. grid (4, 384).
__launch_bounds__(256)
__global__ void ln_project_kernel(const float* __restrict__ act, const float* __restrict__ mask,
                                  const float* __restrict__ ln_scale, const float* __restrict__ ln_offset,
                                  const float* __restrict__ left_b, const float* __restrict__ right_b,
                                  const bf16* __restrict__ projWt,
                                  bf16* __restrict__ leftT, bf16* __restrict__ rightT) {
  __shared__ bf16 At[128 * 264];          // [128 rows][256+8 ch], 67.6 KB
  bf16* outbuf = At;                      // aliased after GEMM: [64 o][136 a]

  const int t = threadIdx.x;
  const int b = blockIdx.y;
  const int a0 = blockIdx.x * 128;

  // ---- phase A: load + stats (2 threads per row) ----
  {
    const int row = t >> 1, h = t & 1;
    const float* p = act + ((size_t)(a0 + row) * N_RES + b) * C_M + h * 128;
    float s1 = 0.f, s2 = 0.f;
#pragma unroll
    for (int i = 0; i < 32; ++i) {
      float4 v = ((const float4*)p)[i];
      s1 += v.x + v.y + v.z + v.w;
      s2 += v.x * v.x + v.y * v.y + v.z * v.z + v.w * v.w;
      bf16x4 tmp;
      tmp[0] = (bf16)v.x; tmp[1] = (bf16)v.y; tmp[2] = (bf16)v.z; tmp[3] = (bf16)v.w;
      *(bf16x4*)&At[row * 264 + h * 128 + i * 4] = tmp;
    }
    s1 += __shfl_xor(s1, 1, 64);
    s2 += __shfl_xor(s2, 1, 64);
    float mean = s1 * (1.f / 256.f);
    float var  = s2 * (1.f / 256.f) - mean * mean;
    float rstd = rsqrtf(var + 1e-5f);
    // normalize own half in place
#pragma unroll
    for (int i = 0; i < 16; ++i) {
      int col = h * 128 + i * 8;
      bf16x8 xv = *(bf16x8*)&At[row * 264 + col];
      float4 g0 = *(const float4*)(ln_scale + col);
      float4 g1 = *(const float4*)(ln_scale + col + 4);
      float4 o0 = *(const float4*)(ln_offset + col);
      float4 o1 = *(const float4*)(ln_offset + col + 4);
      bf16x8 r;
      r[0] = (bf16)(((float)xv[0] - mean) * rstd * g0.x + o0.x);
      r[1] = (bf16)(((float)xv[1] - mean) * rstd * g0.y + o0.y);
      r[2] = (bf16)(((float)xv[2] - mean) * rstd * g0.z + o0.z);
      r[3] = (bf16)(((float)xv[3] - mean) * rstd * g0.w + o0.w);
      r[4] = (bf16)(((float)xv[4] - mean) * rstd * g1.x + o1.x);
      r[5] = (bf16)(((float)xv[5] - mean) * rstd * g1.y + o1.y);
      r[6] = (bf16)(((float)xv[6] - mean) * rstd * g1.z + o1.z);
      r[7] = (bf16)(((float)xv[7] - mean) * rstd * g1.w + o1.w);
      *(bf16x8*)&At[row * 264 + col] = r;
    }
  }
  __syncthreads();

  // ---- phase B: GEMM  D[a_local][o] = actn @ w  (M=128, N=64, K=256) ----
  const int wv = t >> 6, lane = t & 63, q = lane >> 4, l15 = lane & 15;
  f32x4 acc[2][4] = {};
#pragma unroll
  for (int s = 0; s < 8; ++s) {
    bf16x8 af[2], bfr[4];
#pragma unroll
    for (int i = 0; i < 2; ++i)
      af[i] = *(bf16x8*)&At[(wv * 32 + i * 16 + l15) * 264 + s * 32 + q * 8];
#pragma unroll
    for (int j = 0; j < 4; ++j)
      bfr[j] = *(const bf16x8*)&projWt[(j * 16 + l15) * 256 + s * 32 + q * 8];
#pragma unroll
    for (int i = 0; i < 2; ++i)
#pragma unroll
      for (int j = 0; j < 4; ++j)
        acc[i][j] = __builtin_amdgcn_mfma_f32_16x16x32_bf16(af[i], bfr[j], acc[i][j], 0, 0, 0);
  }
  __syncthreads();

  // ---- phase C: bias + mask, stash bf16 into outbuf[o][a_local] ----
#pragma unroll
  for (int i = 0; i < 2; ++i) {
#pragma unroll
    for (int r = 0; r < 4; ++r) {
      int a_local = wv * 32 + i * 16 + q * 4 + r;
      float mv = mask[(size_t)(a0 + a_local) * N_RES + b];
#pragma unroll
      for (int j = 0; j < 4; ++j) {
        int o = j * 16 + l15;
        float bias = (o < 32) ? left_b[o] : right_b[o - 32];
        float val = (acc[i][j][r] + bias) * mv;
        outbuf[o * 136 + a_local] = (bf16)val;
      }
    }
  }
  __syncthreads();

  // ---- phase D: coalesced write to leftT/rightT ----
  {
    int o = t >> 2, part = t & 3;
    bf16* dst = (o < 32) ? (leftT + (size_t)(b * 32 + o) * 512)
                         : (rightT + (size_t)(b * 32 + (o - 32)) * 512);
#pragma unroll
    for (int v = 0; v < 4; ++v) {
      int asub = part * 32 + v * 8;
      bf16x8 val = *(bf16x8*)&outbuf[o * 136 + asub];
      *(bf16x8*)(dst + a0 + asub) = val;
    }
  }
}

// ---------------- main fused kernel: inter tile + W contraction + norm ----------------
// block tile: 128(m = 4b x 32c) x 128(n = 4d x 32e), K=512(a). grid (96,96).
__launch_bounds__(256)
__global__ void outer_kernel(const bf16* __restrict__ leftT, const bf16* __restrict__ rightT,
                             const bf16* __restrict__ WtEp, const float* __restrict__ output_b,
                             const float* __restrict__ recip, float* __restrict__ out) {
  __shared__ union {
    struct { bf16 A[128 * 72]; bf16 B[128 * 72]; } mm;   // 36864 B
    bf16 Aep[16 * 1032];                                 // 33024 B
  } sm;

  const int t = threadIdx.x;
  const int m0 = blockIdx.x * 128;
  const int n0 = blockIdx.y * 128;
  const int wv = t >> 6, lane = t & 63, q = lane >> 4, l15 = lane & 15;
  const int wm = (wv >> 1) * 64, wn = (wv & 1) * 64;

  f32x4 acc[4][4] = {};

  for (int ks = 0; ks < 8; ++ks) {
    __syncthreads();
    // stage A and B tiles: [128][64] bf16 each, pad to 72
#pragma unroll
    for (int i = 0; i < 4; ++i) {
      int c = t + i * 256;                   // 0..1023
      int row = c >> 3, kc = c & 7;
      uint4 va = *(const uint4*)(leftT + (size_t)(m0 + row) * 512 + ks * 64 + kc * 8);
      *(uint4*)&sm.mm.A[row * 72 + kc * 8] = va;
      uint4 vb = *(const uint4*)(rightT + (size_t)(n0 + row) * 512 + ks * 64 + kc * 8);
      *(uint4*)&sm.mm.B[row * 72 + kc * 8] = vb;
    }
    __syncthreads();
#pragma unroll
    for (int s = 0; s < 2; ++s) {
      bf16x8 af[4], bfr[4];
#pragma unroll
      for (int i = 0; i < 4; ++i)
        af[i] = *(bf16x8*)&sm.mm.A[(wm + i * 16 + l15) * 72 + s * 32 + q * 8];
#pragma unroll
      for (int j = 0; j < 4; ++j)
        bfr[j] = *(bf16x8*)&sm.mm.B[(wn + j * 16 + l15) * 72 + s * 32 + q * 8];
#pragma unroll
      for (int i = 0; i < 4; ++i)
#pragma unroll
        for (int j = 0; j < 4; ++j)
          acc[i][j] = __builtin_amdgcn_mfma_f32_16x16x32_bf16(af[i], bfr[j], acc[i][j], 0, 0, 0);
    }
  }
  __syncthreads();

  // scatter inter tile into epilogue-A layout: Aep[pair=bl*4+dl][k=c*32+e]
#pragma unroll
  for (int i = 0; i < 4; ++i) {
#pragma unroll
    for (int r = 0; r < 4; ++r) {
      int m = wm + i * 16 + q * 4 + r;
      int bl = m >> 5, c = m & 31;
#pragma unroll
      for (int j = 0; j < 4; ++j) {
        int n = wn + j * 16 + l15;
        int dl = n >> 5, e = n & 31;
        sm.Aep[(bl * 4 + dl) * 1032 + c * 32 + e] = (bf16)acc[i][j][r];
      }
    }
  }
  __syncthreads();

  // epilogue GEMM: M=16 pairs, N=128 f, K=1024 (c,e). wave wv covers f in [wv*32, wv*32+32)
  f32x4 eacc[2] = {};
  const int fbase = wv * 32;
#pragma unroll
  for (int s = 0; s < 32; ++s) {
    bf16x8 af = *(bf16x8*)&sm.Aep[l15 * 1032 + s * 32 + q * 8];
#pragma unroll
    for (int j = 0; j < 2; ++j) {
      bf16x8 wf = *(const bf16x8*)&WtEp[(size_t)(fbase + j * 16 + l15) * 1024 + s * 32 + q * 8];
      eacc[j] = __builtin_amdgcn_mfma_f32_16x16x32_bf16(af, wf, eacc[j], 0, 0, 0);
    }
  }

  // write: out[b][d][f] = (eacc + output_b[f]) * recip[b][d]
#pragma unroll
  for (int j = 0; j < 2; ++j) {
    int f = fbase + j * 16 + l15;
    float ob = output_b[f];
#pragma unroll
    for (int r = 0; r < 4; ++r) {
      int pair = q * 4 + r;
      int b = (m0 >> 5) + (pair >> 2);
      int d = (n0 >> 5) + (pair & 3);
      float rc = recip[b * N_RES + d];
      out[((size_t)b * N_RES + d) * C_Z + f] = (eacc[j][r] + ob) * rc;
    }
  }
}

extern "C" void kernel_launch(void* const* d_in, const int* in_sizes, int n_in,
                              void* d_out, int out_size, void* d_ws, size_t ws_size,
                              hipStream_t stream) {
  const float* act       = (const float*)d_in[0];
  const float* mask      = (const float*)d_in[1];
  const float* ln_scale  = (const float*)d_in[2];
  const float* ln_offset = (const float*)d_in[3];
  const float* left_w    = (const float*)d_in[4];
  const float* left_b    = (const float*)d_in[5];
  const float* right_w   = (const float*)d_in[6];
  const float* right_b   = (const float*)d_in[7];
  const float* output_w  = (const float*)d_in[8];
  const float* output_b  = (const float*)d_in[9];
  float* out = (float*)d_out;

  char* ws = (char*)d_ws;
  bf16* leftT   = (bf16*)(ws);
  bf16* rightT  = (bf16*)(ws + 12582912);
  bf16* WtEp    = (bf16*)(ws + 25165824);
  bf16* projWt  = (bf16*)(ws + 25427968);
  float* recip  = (float*)(ws + 25460736);

  hipLaunchKernelGGL(prep_kernel, dim3(576), dim3(256), 0, stream,
                     left_w, right_w, output_w, projWt, WtEp);
  hipLaunchKernelGGL(norm_kernel, dim3(24, 24), dim3(16, 16), 0, stream, mask, recip);
  hipLaunchKernelGGL(ln_project_kernel, dim3(4, 384), dim3(256), 0, stream,
                     act, mask, ln_scale, ln_offset, left_b, right_b, projWt, leftT, rightT);
  hipLaunchKernelGGL(outer_kernel, dim3(96, 96), dim3(256), 0, stream,
                     leftT, rightT, WtEp, output_b, recip, out);
}

// Round 2
// 767.398 us; speedup vs baseline: 1.0336x; 1.0336x over previous
//
#include <hip/hip_runtime.h>

#define N_SEQ 512
#define N_RES 384
#define C_M   256
#define C_OUT 32
#define C_Z   128

typedef __bf16 bf16;
typedef __bf16 bf16x4 __attribute__((ext_vector_type(4)));
typedef __bf16 bf16x8 __attribute__((ext_vector_type(8)));
typedef float  f32x4  __attribute__((ext_vector_type(4)));

#define GLDS16(g, l)                                                           \
  __builtin_amdgcn_global_load_lds(                                            \
      (const __attribute__((address_space(1))) void*)(const void*)(g),         \
      (__attribute__((address_space(3))) void*)(void*)(l), 16, 0, 0)

// Workspace layout (bytes):
//   leftT  [12288][512] bf16 @ 0           (m=b*32+c, k=a)   12,582,912
//   rightT [12288][512] bf16 @ 12,582,912  (n=d*32+e, k=a)   12,582,912
//   WtEp   [128][1024]  bf16 @ 25,165,824  (f, ce)              262,144
//   projWt [64][256]    bf16 @ 25,427,968  (o, m)                32,768
//   recip  [384*384]    f32  @ 25,460,736                       589,824

// ---------------- prep: transpose weights to bf16 ----------------
__global__ void prep_kernel(const float* __restrict__ lw, const float* __restrict__ rw,
                            const float* __restrict__ ow,
                            bf16* __restrict__ projWt, bf16* __restrict__ WtEp) {
  int idx = blockIdx.x * 256 + threadIdx.x;
  if (idx < 64 * 256) {
    int o = idx >> 8, m = idx & 255;
    float v = (o < 32) ? lw[m * 32 + o] : rw[m * 32 + (o - 32)];
    projWt[idx] = (bf16)v;               // projWt[o][m]
  } else {
    int i2 = idx - 64 * 256;             // [0, 131072)
    int f = i2 >> 10, k = i2 & 1023;     // k = c*32+e
    WtEp[i2] = (bf16)ow[k * 128 + f];    // WtEp[f][k]
  }
}

// ---------------- norm: recip[b][d] = 1/(eps + sum_a m[a,b] m[a,d]) ----------------
__global__ void norm_kernel(const float* __restrict__ mask, float* __restrict__ recip) {
  int b = blockIdx.x * 16 + threadIdx.x;
  int d = blockIdx.y * 16 + threadIdx.y;
  float s = 0.f;
#pragma unroll 8
  for (int a = 0; a < N_SEQ; ++a)
    s += mask[a * N_RES + b] * mask[a * N_RES + d];
  recip[b * N_RES + d] = 1.0f / (1e-3f + s);
}

// ---------------- LN + projection (MFMA), writes leftT/rightT ----------------
// block: 128 a-rows, fixed b. grid (4, 384). Wave-per-row coalesced loads.
__launch_bounds__(256)
__global__ void ln_project_kernel(const float* __restrict__ act, const float* __restrict__ mask,
                                  const float* __restrict__ ln_scale, const float* __restrict__ ln_offset,
                                  const float* __restrict__ left_b, const float* __restrict__ right_b,
                                  const bf16* __restrict__ projWt,
                                  bf16* __restrict__ leftT, bf16* __restrict__ rightT) {
  __shared__ bf16 At[128 * 264];          // [128 rows][256+8 ch], 67.6 KB
  bf16* outbuf = At;                      // aliased after GEMM: [64 o][136 a]

  const int t = threadIdx.x;
  const int b = blockIdx.y;
  const int a0 = blockIdx.x * 128;
  const int wv = t >> 6, lane = t & 63;

  // ---- phase A: one wave per row, fully coalesced 1KB row loads ----
  {
    const float4 g = *(const float4*)(ln_scale + lane * 4);
    const float4 o = *(const float4*)(ln_offset + lane * 4);
#pragma unroll 4
    for (int it = 0; it < 32; ++it) {
      const int row = it * 4 + wv;
      float4 v = *(const float4*)(act + ((size_t)(a0 + row) * N_RES + b) * C_M + lane * 4);
      float s1 = v.x + v.y + v.z + v.w;
      float s2 = v.x * v.x + v.y * v.y + v.z * v.z + v.w * v.w;
#pragma unroll
      for (int off = 1; off < 64; off <<= 1) {
        s1 += __shfl_xor(s1, off);
        s2 += __shfl_xor(s2, off);
      }
      float mean = s1 * (1.f / 256.f);
      float var  = s2 * (1.f / 256.f) - mean * mean;
      float rstd = rsqrtf(var + 1e-5f);
      bf16x4 r;
      r[0] = (bf16)((v.x - mean) * rstd * g.x + o.x);
      r[1] = (bf16)((v.y - mean) * rstd * g.y + o.y);
      r[2] = (bf16)((v.z - mean) * rstd * g.z + o.z);
      r[3] = (bf16)((v.w - mean) * rstd * g.w + o.w);
      *(bf16x4*)&At[row * 264 + lane * 4] = r;
    }
  }
  __syncthreads();

  // ---- phase B: GEMM  D[a_local][o] = actn @ w  (M=128, N=64, K=256) ----
  const int q = lane >> 4, l15 = lane & 15;
  f32x4 acc[2][4] = {};
#pragma unroll
  for (int s = 0; s < 8; ++s) {
    bf16x8 af[2], bfr[4];
#pragma unroll
    for (int i = 0; i < 2; ++i)
      af[i] = *(bf16x8*)&At[(wv * 32 + i * 16 + l15) * 264 + s * 32 + q * 8];
#pragma unroll
    for (int j = 0; j < 4; ++j)
      bfr[j] = *(const bf16x8*)&projWt[(j * 16 + l15) * 256 + s * 32 + q * 8];
#pragma unroll
    for (int i = 0; i < 2; ++i)
#pragma unroll
      for (int j = 0; j < 4; ++j)
        acc[i][j] = __builtin_amdgcn_mfma_f32_16x16x32_bf16(af[i], bfr[j], acc[i][j], 0, 0, 0);
  }
  __syncthreads();

  // ---- phase C: bias + mask, stash bf16 into outbuf[o][a_local] ----
#pragma unroll
  for (int i = 0; i < 2; ++i) {
#pragma unroll
    for (int r = 0; r < 4; ++r) {
      int a_local = wv * 32 + i * 16 + q * 4 + r;
      float mv = mask[(size_t)(a0 + a_local) * N_RES + b];
#pragma unroll
      for (int j = 0; j < 4; ++j) {
        int o = j * 16 + l15;
        float bias = (o < 32) ? left_b[o] : right_b[o - 32];
        float val = (acc[i][j][r] + bias) * mv;
        outbuf[o * 136 + a_local] = (bf16)val;
      }
    }
  }
  __syncthreads();

  // ---- phase D: coalesced write to leftT/rightT ----
  {
    int o = t >> 2, part = t & 3;
    bf16* dst = (o < 32) ? (leftT + (size_t)(b * 32 + o) * 512)
                         : (rightT + (size_t)(b * 32 + (o - 32)) * 512);
#pragma unroll
    for (int v = 0; v < 4; ++v) {
      int asub = part * 32 + v * 8;
      bf16x8 val = *(bf16x8*)&outbuf[o * 136 + asub];
      *(bf16x8*)(dst + a0 + asub) = val;
    }
  }
}

// ---------------- main fused kernel: inter tile + W contraction + norm ----------------
// block tile: 128(m = 4b x 32c) x 128(n = 4d x 32e), K=512(a). grid 9216 (1-D, swizzled).
// LDS A/B tiles: XOR-swizzled [row][chunk^(row&7)] (chunk = 16B unit) so that
// global_load_lds (lane-ordered dest) and ds_read_b128 frags are both conflict-free.
__launch_bounds__(256)
__global__ void outer_kernel(const bf16* __restrict__ leftT, const bf16* __restrict__ rightT,
                             const bf16* __restrict__ WtEp, const float* __restrict__ output_b,
                             const float* __restrict__ recip, float* __restrict__ out) {
  __shared__ union {
    struct { bf16 A[128 * 64]; bf16 B[128 * 64]; } mm;   // 32768 B
    bf16 Aep[16 * 1288];                                 // 41216 B (pair stride 644 words ≡ 4 mod 32)
  } sm;

  const int t = threadIdx.x;
  // square swizzle: 12x12 supergrid of 8x8 tile squares for L2/L3 locality
  const int sq = blockIdx.x >> 6, wi = blockIdx.x & 63;
  const int m0 = ((sq % 12) * 8 + (wi & 7)) * 128;
  const int n0 = ((sq / 12) * 8 + (wi >> 3)) * 128;

  const int wv = t >> 6, lane = t & 63, q = lane >> 4, l15 = lane & 15;
  const int wm = (wv >> 1) * 64, wn = (wv & 1) * 64;
  const int rl = lane >> 3, pch = lane & 7;   // staging: row_local, physical chunk
  const int lch = pch ^ rl;                   // logical chunk (8 bf16 = 16B)

  char* const smA = (char*)sm.mm.A;
  char* const smB = (char*)sm.mm.B;

  f32x4 acc[4][4] = {};

  for (int ks = 0; ks < 8; ++ks) {
    __syncthreads();
    // stage A,B tiles via global_load_lds (16B/lane, 1KB=8 rows per instr)
#pragma unroll
    for (int it = 0; it < 4; ++it) {
      int rbase = wv * 32 + it * 8;
      GLDS16(leftT + (size_t)(m0 + rbase + rl) * 512 + ks * 64 + lch * 8,
             smA + rbase * 128);
      GLDS16(rightT + (size_t)(n0 + rbase + rl) * 512 + ks * 64 + lch * 8,
             smB + rbase * 128);
    }
    __syncthreads();
#pragma unroll
    for (int s = 0; s < 2; ++s) {
      bf16x8 af[4], bfr[4];
#pragma unroll
      for (int i = 0; i < 4; ++i) {
        int row = wm + i * 16 + l15;
        af[i] = *(bf16x8*)(smA + row * 128 + (((s * 4 + q) ^ (l15 & 7)) * 16));
      }
#pragma unroll
      for (int j = 0; j < 4; ++j) {
        int row = wn + j * 16 + l15;
        bfr[j] = *(bf16x8*)(smB + row * 128 + (((s * 4 + q) ^ (l15 & 7)) * 16));
      }
#pragma unroll
      for (int i = 0; i < 4; ++i)
#pragma unroll
        for (int j = 0; j < 4; ++j)
          acc[i][j] = __builtin_amdgcn_mfma_f32_16x16x32_bf16(af[i], bfr[j], acc[i][j], 0, 0, 0);
    }
  }
  __syncthreads();

  // scatter inter tile into epilogue-A layout: Aep[pair=bl*4+dl][c*40 + e]
#pragma unroll
  for (int i = 0; i < 4; ++i) {
#pragma unroll
    for (int r = 0; r < 4; ++r) {
      int m = wm + i * 16 + q * 4 + r;
      int bl = m >> 5, c = m & 31;
#pragma unroll
      for (int j = 0; j < 4; ++j) {
        int n = wn + j * 16 + l15;
        int dl = n >> 5, e = n & 31;
        sm.Aep[(bl * 4 + dl) * 1288 + c * 40 + e] = (bf16)acc[i][j][r];
      }
    }
  }
  __syncthreads();

  // epilogue GEMM: M=16 pairs, N=128 f, K=1024 (c,e). wave wv covers f in [wv*32, wv*32+32)
  f32x4 eacc[2] = {};
  const int fbase = wv * 32;
#pragma unroll
  for (int s = 0; s < 32; ++s) {
    bf16x8 af = *(bf16x8*)&sm.Aep[l15 * 1288 + s * 40 + q * 8];
#pragma unroll
    for (int j = 0; j < 2; ++j) {
      bf16x8 wf = *(const bf16x8*)&WtEp[(size_t)(fbase + j * 16 + l15) * 1024 + s * 32 + q * 8];
      eacc[j] = __builtin_amdgcn_mfma_f32_16x16x32_bf16(af, wf, eacc[j], 0, 0, 0);
    }
  }

  // write: out[b][d][f] = (eacc + output_b[f]) * recip[b][d]
#pragma unroll
  for (int j = 0; j < 2; ++j) {
    int f = fbase + j * 16 + l15;
    float ob = output_b[f];
#pragma unroll
    for (int r = 0; r < 4; ++r) {
      int pair = q * 4 + r;
      int b = (m0 >> 5) + (pair >> 2);
      int d = (n0 >> 5) + (pair & 3);
      float rc = recip[b * N_RES + d];
      out[((size_t)b * N_RES + d) * C_Z + f] = (eacc[j][r] + ob) * rc;
    }
  }
}

extern "C" void kernel_launch(void* const* d_in, const int* in_sizes, int n_in,
                              void* d_out, int out_size, void* d_ws, size_t ws_size,
                              hipStream_t stream) {
  const float* act       = (const float*)d_in[0];
  const float* mask      = (const float*)d_in[1];
  const float* ln_scale  = (const float*)d_in[2];
  const float* ln_offset = (const float*)d_in[3];
  const float* left_w    = (const float*)d_in[4];
  const float* left_b    = (const float*)d_in[5];
  const float* right_w   = (const float*)d_in[6];
  const float* right_b   = (const float*)d_in[7];
  const float* output_w  = (const float*)d_in[8];
  const float* output_b  = (const float*)d_in[9];
  float* out = (float*)d_out;

  char* ws = (char*)d_ws;
  bf16* leftT   = (bf16*)(ws);
  bf16* rightT  = (bf16*)(ws + 12582912);
  bf16* WtEp    = (bf16*)(ws + 25165824);
  bf16* projWt  = (bf16*)(ws + 25427968);
  float* recip  = (float*)(ws + 25460736);

  hipLaunchKernelGGL(prep_kernel, dim3(576), dim3(256), 0, stream,
                     left_w, right_w, output_w, projWt, WtEp);
  hipLaunchKernelGGL(norm_kernel, dim3(24, 24), dim3(16, 16), 0, stream, mask, recip);
  hipLaunchKernelGGL(ln_project_kernel, dim3(4, 384), dim3(256), 0, stream,
                     act, mask, ln_scale, ln_offset, left_b, right_b, projWt, leftT, rightT);
  hipLaunchKernelGGL(outer_kernel, dim3(9216), dim3(256), 0, stream,
                     leftT, rightT, WtEp, output_b, recip, out);
}

// Round 3
// 631.945 us; speedup vs baseline: 1.2552x; 1.2143x over previous
//
#include <hip/hip_runtime.h>

#define N_SEQ 512
#define N_RES 384
#define C_M   256

typedef __bf16 bf16;
typedef __bf16 bf16x4 __attribute__((ext_vector_type(4)));
typedef __bf16 bf16x8 __attribute__((ext_vector_type(8)));
typedef float  f32x4  __attribute__((ext_vector_type(4)));
typedef float  f32x16 __attribute__((ext_vector_type(16)));

static __device__ __forceinline__ bf16x8 ld8(const bf16* p) {
  bf16x4 lo = *(const bf16x4*)p;
  bf16x4 hi = *(const bf16x4*)(p + 4);
  bf16x8 r;
  r[0] = lo[0]; r[1] = lo[1]; r[2] = lo[2]; r[3] = lo[3];
  r[4] = hi[0]; r[5] = hi[1]; r[6] = hi[2]; r[7] = hi[3];
  return r;
}

// Workspace layout (bytes):
//   leftT  [12288][512] bf16 @ 0          (m=b*32+c, k=a)
//   rightT [12288][512] bf16 @ 12582912   (n=d*32+e, k=a)
//   WtEp   [128][1024]  bf16 @ 25165824   (f, k=e*32+c)  e-major!
//   projW2 [64][256]    bf16 @ 25427968   (o, m)  = g[m]*w[m][o]
//   Svec   [64] f32     @ 25460736        column sums of projW2
//   bias2  [64] f32     @ 25460992        bias + o@w
//   recip  [384*384] f32 @ 25461248

// ---------------- aux: norm + weight prep, one launch ----------------
__global__ void aux_kernel(const float* __restrict__ mask,
                           const float* __restrict__ lw, const float* __restrict__ rw,
                           const float* __restrict__ ow,
                           const float* __restrict__ ln_scale, const float* __restrict__ ln_offset,
                           const float* __restrict__ left_b, const float* __restrict__ right_b,
                           bf16* __restrict__ projW2, bf16* __restrict__ WtEp,
                           float* __restrict__ Svec, float* __restrict__ bias2,
                           float* __restrict__ recip) {
  int blk = blockIdx.x, t = threadIdx.x;
  if (blk < 576) {
    int bx = blk % 24, by = blk / 24;
    int b = bx * 16 + (t & 15), d = by * 16 + (t >> 4);
    float s = 0.f;
#pragma unroll 8
    for (int a = 0; a < N_SEQ; ++a)
      s += mask[a * N_RES + b] * mask[a * N_RES + d];
    recip[b * N_RES + d] = 1.0f / (1e-3f + s);
  } else if (blk < 1088) {
    int i2 = (blk - 576) * 256 + t;          // [0, 131072)
    int f = i2 >> 10, k = i2 & 1023, e = k >> 5, c = k & 31;
    WtEp[i2] = (bf16)ow[(c * 32 + e) * 128 + f];   // WtEp[f][e*32+c]
  } else if (blk < 1152) {
    int idx = (blk - 1088) * 256 + t;        // [0, 16384)
    int o = idx >> 8, m = idx & 255;
    float w = (o < 32) ? lw[m * 32 + o] : rw[m * 32 + (o - 32)];
    projW2[idx] = (bf16)(ln_scale[m] * w);
  } else {
    if (t < 64) {
      int o = t;
      float s = 0.f, b2 = (o < 32) ? left_b[o] : right_b[o - 32];
      for (int m = 0; m < 256; ++m) {
        float w = (o < 32) ? lw[m * 32 + o] : rw[m * 32 + (o - 32)];
        s += (float)(bf16)(ln_scale[m] * w);   // match MFMA's bf16 W' exactly
        b2 += ln_offset[m] * w;
      }
      Svec[o] = s; bias2[o] = b2;
    }
  }
}

// ---------------- LN + projection: stats via LDS pass, mean-correction post-GEMM ----------------
// block: 128 a-rows, fixed b. grid (4, 384).
__launch_bounds__(256)
__global__ void ln_project_kernel(const float* __restrict__ act, const float* __restrict__ mask,
                                  const bf16* __restrict__ projW2,
                                  const float* __restrict__ Svec, const float* __restrict__ bias2,
                                  bf16* __restrict__ leftT, bf16* __restrict__ rightT) {
  __shared__ __align__(16) bf16 At[128 * 264];   // raw bf16 x, [128][256+8]
  __shared__ float2 muRow[128];
  bf16* outbuf = At;                             // aliased after GEMM: [64 o][136 a]

  const int t = threadIdx.x;
  const int b = blockIdx.y;
  const int a0 = blockIdx.x * 128;
  const int wv = t >> 6, lane = t & 63;
  const int q = lane >> 4, l15 = lane & 15;

  // ---- A: coalesced 1KB row loads, store raw bf16 ----
#pragma unroll 4
  for (int it = 0; it < 32; ++it) {
    const int row = it * 4 + wv;
    float4 v = *(const float4*)(act + ((size_t)(a0 + row) * N_RES + b) * C_M + lane * 4);
    bf16x4 r;
    r[0] = (bf16)v.x; r[1] = (bf16)v.y; r[2] = (bf16)v.z; r[3] = (bf16)v.w;
    *(bf16x4*)&At[row * 264 + lane * 4] = r;
  }
  __syncthreads();

  // ---- A2: per-half-row stats from LDS (no butterfly storm) ----
  {
    int row = t >> 1, half = t & 1;
    const bf16* base = At + row * 264 + half * 128;
    float s1 = 0.f, s2 = 0.f;
#pragma unroll
    for (int i = 0; i < 16; ++i) {
      int ch = ((i + row) & 15) * 8;             // rotation breaks bank collisions
      bf16x8 v = *(const bf16x8*)(base + ch);
#pragma unroll
      for (int u = 0; u < 8; ++u) { float x = (float)v[u]; s1 += x; s2 += x * x; }
    }
    s1 += __shfl_xor(s1, 1);
    s2 += __shfl_xor(s2, 1);
    if (half == 0) {
      float mean = s1 * (1.f / 256.f);
      float var  = s2 * (1.f / 256.f) - mean * mean;
      muRow[row] = make_float2(mean, rsqrtf(var + 1e-5f));
    }
  }

  // ---- B: GEMM raw x @ W'  (M=128, N=64, K=256) ----
  f32x4 acc[2][4] = {};
#pragma unroll
  for (int s = 0; s < 8; ++s) {
    bf16x8 af[2], bfr[4];
#pragma unroll
    for (int i = 0; i < 2; ++i)
      af[i] = *(bf16x8*)&At[(wv * 32 + i * 16 + l15) * 264 + s * 32 + q * 8];
#pragma unroll
    for (int j = 0; j < 4; ++j)
      bfr[j] = *(const bf16x8*)&projW2[(j * 16 + l15) * 256 + s * 32 + q * 8];
#pragma unroll
    for (int i = 0; i < 2; ++i)
#pragma unroll
      for (int j = 0; j < 4; ++j)
        acc[i][j] = __builtin_amdgcn_mfma_f32_16x16x32_bf16(af[i], bfr[j], acc[i][j], 0, 0, 0);
  }
  __syncthreads();

  // ---- C: z = rstd*(P - mu*S) + bias2, then *mask ----
  float Sv[4], Bv[4];
#pragma unroll
  for (int j = 0; j < 4; ++j) { Sv[j] = Svec[j * 16 + l15]; Bv[j] = bias2[j * 16 + l15]; }
#pragma unroll
  for (int i = 0; i < 2; ++i) {
#pragma unroll
    for (int r = 0; r < 4; ++r) {
      int a_local = wv * 32 + i * 16 + q * 4 + r;
      float2 ms = muRow[a_local];
      float mv = mask[(size_t)(a0 + a_local) * N_RES + b];
#pragma unroll
      for (int j = 0; j < 4; ++j) {
        float val = (ms.y * (acc[i][j][r] - ms.x * Sv[j]) + Bv[j]) * mv;
        outbuf[(j * 16 + l15) * 136 + a_local] = (bf16)val;
      }
    }
  }
  __syncthreads();

  // ---- D: coalesced write to leftT/rightT ----
  {
    int o = t >> 2, part = t & 3;
    bf16* dst = (o < 32) ? (leftT + (size_t)(b * 32 + o) * 512)
                         : (rightT + (size_t)(b * 32 + (o - 32)) * 512);
#pragma unroll
    for (int v = 0; v < 4; ++v) {
      int asub = part * 32 + v * 8;
      bf16x8 val = *(bf16x8*)&outbuf[o * 136 + asub];
      *(bf16x8*)(dst + a0 + asub) = val;
    }
  }
}

// ---------------- main kernel: 256x256 tile, 512 thr, 32x32x16 MFMA, B direct-global ----------------
__launch_bounds__(512, 2)
__global__ void outer_kernel(const bf16* __restrict__ leftT, const bf16* __restrict__ rightT,
                             const bf16* __restrict__ WtEp, const float* __restrict__ output_b,
                             const float* __restrict__ recip, float* __restrict__ out) {
  __shared__ __align__(16) union {
    bf16 A[256 * 68];        // 34816 B : staged A chunk, padded stride 68 hw
    bf16 Aep[64 * 1156];     // 147968 B: inter tile, [pair][e*36 + c]
    float P[4 * 64 * 2 * 64];// 131072 B: epilogue partials [kq][pair][fh][fl]
  } sm;

  const int t = threadIdx.x;
  const int sq = blockIdx.x >> 4, wi = blockIdx.x & 15;
  const int m0 = ((sq % 12) * 4 + (wi & 3)) * 256;
  const int n0 = ((sq / 12) * 4 + (wi >> 2)) * 256;

  const int wv = t >> 6, lane = t & 63;
  const int q = lane >> 4, l15 = lane & 15;
  const int l31 = lane & 31, h = lane >> 5;
  const int wm = (wv & 1) * 128, wn = (wv >> 1) * 64;

  // A staging assignment: wave wv stages rows wv*32 .. wv*32+32
  const int srow = wv * 32 + (lane >> 3);        // + w*8
  const int skc  = lane & 7;                     // logical 16B chunk (k)
  const int sphys = skc ^ (lane >> 3);           // XOR-swizzled physical chunk

  f32x16 acc[4][2] = {};
  uint4 areg[4];
#pragma unroll
  for (int w = 0; w < 4; ++w)
    areg[w] = *(const uint4*)(leftT + (size_t)(m0 + srow + w * 8) * 512 + skc * 8);

  for (int ks = 0; ks < 8; ++ks) {
    __syncthreads();
#pragma unroll
    for (int w = 0; w < 4; ++w) {
      int off = (srow + w * 8) * 68 + sphys * 8;
      *(uint2*)&sm.A[off]     = make_uint2(areg[w].x, areg[w].y);
      *(uint2*)&sm.A[off + 4] = make_uint2(areg[w].z, areg[w].w);
    }
    __syncthreads();
    if (ks < 7) {
#pragma unroll
      for (int w = 0; w < 4; ++w)
        areg[w] = *(const uint4*)(leftT + (size_t)(m0 + srow + w * 8) * 512 + (ks + 1) * 64 + skc * 8);
    }
    // B frags direct from global (L1/L2 pipe), software-pipelined over s
    const bf16* Bbase = rightT + (size_t)(n0 + wn) * 512 + ks * 64 + h * 8;
    bf16x8 bc0 = *(const bf16x8*)(Bbase + (size_t)l31 * 512);
    bf16x8 bc1 = *(const bf16x8*)(Bbase + (size_t)(32 + l31) * 512);
#pragma unroll
    for (int s = 0; s < 4; ++s) {
      bf16x8 bn0, bn1;
      if (s < 3) {
        bn0 = *(const bf16x8*)(Bbase + (size_t)l31 * 512 + (s + 1) * 16);
        bn1 = *(const bf16x8*)(Bbase + (size_t)(32 + l31) * 512 + (s + 1) * 16);
      }
      bf16x8 af[4];
      int kc = s * 2 + h;
#pragma unroll
      for (int i = 0; i < 4; ++i)
        af[i] = ld8(&sm.A[(wm + i * 32 + l31) * 68 + ((kc ^ (l31 & 7)) * 8)]);
#pragma unroll
      for (int i = 0; i < 4; ++i) {
        acc[i][0] = __builtin_amdgcn_mfma_f32_32x32x16_bf16(af[i], bc0, acc[i][0], 0, 0, 0);
        acc[i][1] = __builtin_amdgcn_mfma_f32_32x32x16_bf16(af[i], bc1, acc[i][1], 0, 0, 0);
      }
      bc0 = bn0; bc1 = bn1;
    }
  }
  __syncthreads();

  // scatter inter tile -> Aep[pair][e*36 + c], b64-packed (4 consecutive c per reg-group)
#pragma unroll
  for (int i = 0; i < 4; ++i) {
#pragma unroll
    for (int j = 0; j < 2; ++j) {
      int pair = ((wv & 1) * 4 + i) * 8 + (wv >> 1) * 2 + j;
      int base = pair * 1156 + l31 * 36;   // e = l31
#pragma unroll
      for (int g = 0; g < 4; ++g) {
        bf16x4 v;
        v[0] = (bf16)acc[i][j][4 * g + 0];
        v[1] = (bf16)acc[i][j][4 * g + 1];
        v[2] = (bf16)acc[i][j][4 * g + 2];
        v[3] = (bf16)acc[i][j][4 * g + 3];
        *(bf16x4*)&sm.Aep[base + 8 * g + 4 * h] = v;   // c = 8g+4h+{0..3}
      }
    }
  }
  __syncthreads();

  // epilogue: each wave: k-slice 256 (kq), f-slice 64 (fh), all 64 pairs. W read once/block.
  const int kq = wv & 3, fh = wv >> 2;
  f32x4 eacc[4][4] = {};   // [mt][j]
#pragma unroll
  for (int si = 0; si < 8; ++si) {
    int e = kq * 8 + si;
    bf16x8 wf[4];
#pragma unroll
    for (int j = 0; j < 4; ++j)
      wf[j] = *(const bf16x8*)&WtEp[(size_t)(fh * 64 + j * 16 + l15) * 1024 + e * 32 + q * 8];
    bf16x8 af[4];
#pragma unroll
    for (int mt = 0; mt < 4; ++mt)
      af[mt] = ld8(&sm.Aep[(mt * 16 + l15) * 1156 + e * 36 + q * 8]);
#pragma unroll
    for (int mt = 0; mt < 4; ++mt)
#pragma unroll
      for (int j = 0; j < 4; ++j)
        eacc[mt][j] = __builtin_amdgcn_mfma_f32_16x16x32_bf16(af[mt], wf[j], eacc[mt][j], 0, 0, 0);
  }
  __syncthreads();

  // write partials P[kq][pair][fh][fl]
#pragma unroll
  for (int mt = 0; mt < 4; ++mt)
#pragma unroll
    for (int j = 0; j < 4; ++j)
#pragma unroll
      for (int r = 0; r < 4; ++r) {
        int pair = mt * 16 + q * 4 + r;
        int fl = j * 16 + l15;
        sm.P[((kq * 64 + pair) * 2 + fh) * 64 + fl] = eacc[mt][j][r];
      }
  __syncthreads();

  // reduce over kq, add bias, scale by recip, write out
#pragma unroll
  for (int gg = 0; gg < 4; ++gg) {
    int g = t + 512 * gg;          // [0, 2048)
    int pair = g >> 5, f4 = g & 31;
    int f = f4 * 4, fh2 = f >> 6, fl = f & 63;
    f32x4 s = {};
#pragma unroll
    for (int k2 = 0; k2 < 4; ++k2)
      s += *(f32x4*)&sm.P[((k2 * 64 + pair) * 2 + fh2) * 64 + fl];
    int b = (m0 >> 5) + (pair >> 3);
    int d = (n0 >> 5) + (pair & 7);
    float rc = recip[b * N_RES + d];
    float4 ob = *(const float4*)(output_b + f);
    f32x4 o;
    o[0] = (s[0] + ob.x) * rc; o[1] = (s[1] + ob.y) * rc;
    o[2] = (s[2] + ob.z) * rc; o[3] = (s[3] + ob.w) * rc;
    *(f32x4*)(out + ((size_t)b * N_RES + d) * 128 + f) = o;
  }
}

extern "C" void kernel_launch(void* const* d_in, const int* in_sizes, int n_in,
                              void* d_out, int out_size, void* d_ws, size_t ws_size,
                              hipStream_t stream) {
  const float* act       = (const float*)d_in[0];
  const float* mask      = (const float*)d_in[1];
  const float* ln_scale  = (const float*)d_in[2];
  const float* ln_offset = (const float*)d_in[3];
  const float* left_w    = (const float*)d_in[4];
  const float* left_b    = (const float*)d_in[5];
  const float* right_w   = (const float*)d_in[6];
  const float* right_b   = (const float*)d_in[7];
  const float* output_w  = (const float*)d_in[8];
  const float* output_b  = (const float*)d_in[9];
  float* out = (float*)d_out;

  char* ws = (char*)d_ws;
  bf16* leftT   = (bf16*)(ws);
  bf16* rightT  = (bf16*)(ws + 12582912);
  bf16* WtEp    = (bf16*)(ws + 25165824);
  bf16* projW2  = (bf16*)(ws + 25427968);
  float* Svec   = (float*)(ws + 25460736);
  float* bias2  = (float*)(ws + 25460992);
  float* recip  = (float*)(ws + 25461248);

  hipLaunchKernelGGL(aux_kernel, dim3(1153), dim3(256), 0, stream,
                     mask, left_w, right_w, output_w, ln_scale, ln_offset,
                     left_b, right_b, projW2, WtEp, Svec, bias2, recip);
  hipLaunchKernelGGL(ln_project_kernel, dim3(4, 384), dim3(256), 0, stream,
                     act, mask, projW2, Svec, bias2, leftT, rightT);
  hipLaunchKernelGGL(outer_kernel, dim3(2304), dim3(512), 0, stream,
                     leftT, rightT, WtEp, output_b, recip, out);
}